// Round 6
// baseline (166.224 us; speedup 1.0000x reference)
//
#include <hip/hip_runtime.h>

#define NPTS 131072

// ---------- folded-weight table layout in d_ws (f32 elements) ----------
constexpr int OFF_SW1 = 0;        // 1024  select_w1 TRANSPOSED [c*32+e]
constexpr int OFF_BNS = 1024;     // 32    bn scale (gamma/sqrt(var+eps))
constexpr int OFF_BNH = 1056;     // 32    bn shift (beta - mean*scale)
constexpr int OFF_SW2 = 1088;     // 32
constexpr int OFF_B2  = 1120;     // 1
constexpr int OFF_QG  = 1121;     // 608   wq @ Gk^T   [e*19+k]
constexpr int OFF_QGB = 1729;     // 19    bq @ Gk^T
constexpr int OFF_QM  = 1748;     // 96    wq @ Mk^T   [e*3+m]
constexpr int OFF_QMB = 1844;     // 3     bq @ Mk^T
constexpr int OFF_QBV = 1847;     // 32    wq @ bk
constexpr int OFF_QBB = 1879;     // 1     bq . bk
constexpr int OFF_A1  = 1880;     // 608   wt_top @ w_out  [e*19+j]
constexpr int OFF_GVB = 2488;     // 361   Gv @ B  [k*19+j]   (B = wo @ wt_bot @ w_out)
constexpr int OFF_MVB = 2849;     // 57    Mv @ B  [m*19+j]
constexpr int OFF_CV  = 2906;     // 19    bv@B + bo@A2
constexpr int OFF_BB  = 2925;     // 19    bt@w_out + b_out
// table = 2944 floats = 46 regs x 64 lanes exactly
// ---- intermediates (ws scratch past the table) ----
constexpr int XG   = 3072;  // 608  G[k*32+e]
constexpr int XA2  = 3680;  // 608  A2[d*19+j]
constexpr int XMK  = 4288;  // 96   Mk[m*32+c]
constexpr int XMV  = 4384;  // 96   Mv[m*32+c]
constexpr int XGK  = 4480;  // 608  Gk[k*32+c]
constexpr int XGV  = 5088;  // 608  Gv[k*32+c]
constexpr int XB   = 5696;  // 608  B[c*19+j]

// =====================================================================
// Precompute stage A: everything independent (wide, one elem per thread)
// =====================================================================
__global__ __launch_bounds__(256) void pre_a(
    const float* __restrict__ z,
    const float* __restrict__ sw1,
    const float* __restrict__ bn_gamma, const float* __restrict__ bn_beta,
    const float* __restrict__ bn_mean,  const float* __restrict__ bn_var,
    const float* __restrict__ sw2,      const float* __restrict__ sb2,
    const float* __restrict__ wq, const float* __restrict__ bq,
    const float* __restrict__ wk, const float* __restrict__ bk,
    const float* __restrict__ wv,
    const float* __restrict__ wt, const float* __restrict__ bt,
    const float* __restrict__ wout, const float* __restrict__ bout,
    const float* __restrict__ wgen, const float* __restrict__ bgen,
    float* __restrict__ W)
{
    int i = blockIdx.x * 256 + threadIdx.x;
    if (i < 1024) {                       // SW1T[c*32+e] = sw1[e*32+c]
        W[OFF_SW1 + i] = sw1[(i & 31) * 32 + (i >> 5)];
    } else if (i < 1632) {                // A1, A2
        int t = i - 1024, e = t / 19, j = t % 19;
        float a1 = 0.f, a2 = 0.f;
        for (int d = 0; d < 32; ++d) {
            float w_ = wout[d*19 + j];
            a1 += wt[e*32 + d] * w_;
            a2 += wt[(32 + e)*32 + d] * w_;
        }
        W[OFF_A1 + t] = a1; W[XA2 + t] = a2;
    } else if (i < 2240) {                // G[k*32+e] = g0[e] + wc[k][e]
        int t = i - 1632, k = t >> 5, e = t & 31;
        float g = bgen[e];
        for (int d = 0; d < 16; ++d) g += z[d] * wgen[d*32 + e];
        W[XG + t] = g + wgen[(16 + k)*32 + e];
    } else if (i < 2336) {                // Mk, Mv
        int t = i - 2240, m = t >> 5, c = t & 31;
        float a = 0.f, b = 0.f;
        for (int e = 0; e < 32; ++e) {
            float wsr = wgen[(35 + m)*32 + e];
            a += wsr * wk[e*32 + c];
            b += wsr * wv[e*32 + c];
        }
        W[XMK + t] = a; W[XMV + t] = b;
    } else if (i < 2368) {                // BN fold + SW2
        int t = i - 2336;
        float scale = bn_gamma[t] / sqrtf(bn_var[t] + 1e-4f);
        W[OFF_BNS + t] = scale;
        W[OFF_BNH + t] = bn_beta[t] - bn_mean[t] * scale;
        W[OFF_SW2 + t] = sw2[t];
    } else if (i < 2387) {                // bb = bt@wout + bout
        int t = i - 2368;
        float a = bout[t];
        for (int d = 0; d < 32; ++d) a += bt[d] * wout[d*19 + t];
        W[OFF_BB + t] = a;
    } else if (i < 2419) {                // qbv = wq @ bk
        int t = i - 2387;
        float a = 0.f;
        for (int c = 0; c < 32; ++c) a += wq[t*32 + c] * bk[c];
        W[OFF_QBV + t] = a;
    } else if (i == 2419) {               // b2
        W[OFF_B2] = sb2[0];
    } else if (i == 2420) {               // qbb = bq . bk
        float a = 0.f;
        for (int c = 0; c < 32; ++c) a += bq[c] * bk[c];
        W[OFF_QBB] = a;
    }
}

// =====================================================================
// Precompute stage B: Gk, Gv, B, QM, QMB (reads A's intermediates)
// =====================================================================
__global__ __launch_bounds__(256) void pre_b(
    const float* __restrict__ wq, const float* __restrict__ bq,
    const float* __restrict__ wk, const float* __restrict__ wv,
    const float* __restrict__ wo,
    float* __restrict__ W)
{
    int i = blockIdx.x * 256 + threadIdx.x;
    if (i < 608) {                        // Gk, Gv  [k*32+c]
        int k = i >> 5, c = i & 31;
        float a = 0.f, b = 0.f;
        for (int e = 0; e < 32; ++e) {
            float g = W[XG + k*32 + e];
            a += g * wk[e*32 + c];
            b += g * wv[e*32 + c];
        }
        W[XGK + i] = a; W[XGV + i] = b;
    } else if (i < 1216) {                // B[c*19+j] = wo @ A2
        int t = i - 608, c = t / 19, j = t % 19;
        float a = 0.f;
        for (int d = 0; d < 32; ++d) a += wo[c*32 + d] * W[XA2 + d*19 + j];
        W[XB + t] = a;
    } else if (i < 1312) {                // QM[e*3+m] = wq @ Mk^T
        int t = i - 1216, e = t / 3, m = t % 3;
        float a = 0.f;
        for (int c = 0; c < 32; ++c) a += wq[e*32 + c] * W[XMK + m*32 + c];
        W[OFF_QM + t] = a;
    } else if (i < 1315) {                // QMB[m] = bq @ Mk^T
        int m = i - 1312;
        float a = 0.f;
        for (int c = 0; c < 32; ++c) a += bq[c] * W[XMK + m*32 + c];
        W[OFF_QMB + m] = a;
    }
}

// =====================================================================
// Precompute stage C: QG, QGB, GVB, MVB, CV (reads B's intermediates)
// =====================================================================
__global__ __launch_bounds__(256) void pre_c(
    const float* __restrict__ wq, const float* __restrict__ bq,
    const float* __restrict__ bv, const float* __restrict__ bo,
    float* __restrict__ W)
{
    int i = blockIdx.x * 256 + threadIdx.x;
    if (i < 608) {                        // QG[e*19+k] = wq @ Gk^T
        int e = i / 19, k = i % 19;
        float a = 0.f;
        for (int c = 0; c < 32; ++c) a += wq[e*32 + c] * W[XGK + k*32 + c];
        W[OFF_QG + i] = a;
    } else if (i < 627) {                 // QGB[k] = bq @ Gk^T
        int k = i - 608;
        float a = 0.f;
        for (int c = 0; c < 32; ++c) a += bq[c] * W[XGK + k*32 + c];
        W[OFF_QGB + k] = a;
    } else if (i < 988) {                 // GVB[k*19+j] = Gv @ B
        int t = i - 627, k = t / 19, j = t % 19;
        float a = 0.f;
        for (int c = 0; c < 32; ++c) a += W[XGV + k*32 + c] * W[XB + c*19 + j];
        W[OFF_GVB + t] = a;
    } else if (i < 1045) {                // MVB[m*19+j] = Mv @ B
        int t = i - 988, m = t / 19, j = t % 19;
        float a = 0.f;
        for (int c = 0; c < 32; ++c) a += W[XMV + m*32 + c] * W[XB + c*19 + j];
        W[OFF_MVB + t] = a;
    } else if (i < 1064) {                // CV[j] = bv@B + bo@A2
        int j = i - 1045;
        float a = 0.f;
        for (int c = 0; c < 32; ++c) a += bv[c] * W[XB + c*19 + j];
        for (int d = 0; d < 32; ++d) a += bo[d] * W[XA2 + d*19 + j];
        W[OFF_CV + j] = a;
    }
}

// =====================================================================
// Kernel 2: one point per thread. Whole folded table (2944 f32) lives in
// 46 lane-distributed VGPRs per wave (ext_vector values -> cannot be
// demoted to scratch). Each weight access = v_readlane (VGPR->SGPR
// broadcast, zero memory latency) feeding v_fmac with an SGPR operand.
// =====================================================================
typedef float vf16 __attribute__((ext_vector_type(16)));

// reg r of the table: r<16 -> t0, r<32 -> t1, else t2 (indices constexpr
// after full unroll; ternaries + extractelement fold to a single register)
#define TREG(r) ((r) < 16 ? t0[(r)] : ((r) < 32 ? t1[(r)-16] : t2[(r)-32]))
// weight i of the table: reg i/64, lane i%64
#define RLW(i) __int_as_float(__builtin_amdgcn_readlane(__float_as_int(TREG((i) >> 6)), (i) & 63))

__global__ __launch_bounds__(256, 1) void main_k(
    const float* __restrict__ feat,
    const float* __restrict__ sflow,
    const float* __restrict__ cpred,
    const float* __restrict__ Wg,
    float* __restrict__ out)
{
    const int n = blockIdx.x * 256 + threadIdx.x;
    const int lane = threadIdx.x & 63;

    // ---- load the folded table into lane-distributed VGPRs (coalesced) ----
    vf16 t0, t1, t2;
#pragma unroll
    for (int r = 0; r < 16; ++r) t0[r] = Wg[r * 64 + lane];
#pragma unroll
    for (int r = 0; r < 16; ++r) t1[r] = Wg[(16 + r) * 64 + lane];
#pragma unroll
    for (int r = 0; r < 14; ++r) t2[r] = Wg[(32 + r) * 64 + lane];
    t2[14] = 0.f; t2[15] = 0.f;

    // ---- load feat row (32 f32, 128B aligned) ----
    float f[32];
    const float4* fp = (const float4*)(feat + (long)n * 32);
#pragma unroll
    for (int g = 0; g < 8; ++g) {
        float4 v = fp[g];
        f[g*4+0] = v.x; f[g*4+1] = v.y; f[g*4+2] = v.z; f[g*4+3] = v.w;
    }

    // ---- scene_flow + temp mask ----
    float s0 = sflow[(long)n*3 + 0];
    float s1 = sflow[(long)n*3 + 1];
    float s2 = sflow[(long)n*3 + 2];
    bool tmask = (s0 != 0.f) | (s1 != 0.f) | (s2 != 0.f);

    // ---- softmax(coarse_pred) ----
    float cp[19];
#pragma unroll
    for (int k = 0; k < 19; ++k) cp[k] = cpred[(long)n*19 + k];
    float m1 = cp[0];
#pragma unroll
    for (int k = 1; k < 19; ++k) m1 = fmaxf(m1, cp[k]);
    float sum1 = 0.f;
#pragma unroll
    for (int k = 0; k < 19; ++k) { cp[k] = __expf(cp[k] - m1); sum1 += cp[k]; }
    float r1 = 1.f / sum1;
#pragma unroll
    for (int k = 0; k < 19; ++k) cp[k] *= r1;

    // ---- selection score (exact f32, same op order as round 5) ----
    float sacc = RLW(OFF_B2);
#pragma unroll
    for (int c = 0; c < 32; ++c) {
        float a = 0.f;
#pragma unroll
        for (int e = 0; e < 32; ++e) a = fmaf(f[e], RLW(OFF_SW1 + c*32 + e), a);
        float h = fmaf(a, RLW(OFF_BNS + c), RLW(OFF_BNH + c));
        h = fmaxf(h, 0.f);
        sacc = fmaf(h, RLW(OFF_SW2 + c), sacc);
    }
    // sigmoid(s) < 0.8  <=>  s < ln(4)
    bool valid = tmask && (sacc < 1.3862943611198906f);

    // ---- attention logits via folded weights ----
    float qg[19];
#pragma unroll
    for (int k = 0; k < 19; ++k) qg[k] = RLW(OFF_QGB + k);
    float qm0 = RLW(OFF_QMB + 0), qm1 = RLW(OFF_QMB + 1), qm2 = RLW(OFF_QMB + 2);
    float qb = RLW(OFF_QBB);
#pragma unroll
    for (int e = 0; e < 32; ++e) {
        float fe = f[e];
#pragma unroll
        for (int k = 0; k < 19; ++k) qg[k] = fmaf(fe, RLW(OFF_QG + e*19 + k), qg[k]);
        qm0 = fmaf(fe, RLW(OFF_QM + e*3 + 0), qm0);
        qm1 = fmaf(fe, RLW(OFF_QM + e*3 + 1), qm1);
        qm2 = fmaf(fe, RLW(OFF_QM + e*3 + 2), qm2);
        qb  = fmaf(fe, RLW(OFF_QBV + e), qb);
    }
    float qs = s0*qm0 + s1*qm1 + s2*qm2;

    const float RS = 0.17677669529663687f;  // 1/sqrt(32)
    float l[19];
#pragma unroll
    for (int k = 0; k < 19; ++k) l[k] = fmaf(cp[k], qg[k] + qs, qb) * RS;

    // ---- softmax(l) -> attn;  w[k] = attn[k]*cp[k];  Sw = sum w ----
    float m2 = l[0];
#pragma unroll
    for (int k = 1; k < 19; ++k) m2 = fmaxf(m2, l[k]);
    float sum2 = 0.f;
#pragma unroll
    for (int k = 0; k < 19; ++k) { l[k] = __expf(l[k] - m2); sum2 += l[k]; }
    float r2 = 1.f / sum2;
    float Sw = 0.f;
#pragma unroll
    for (int k = 0; k < 19; ++k) { l[k] = l[k] * r2 * cp[k]; Sw += l[k]; }

    // ---- o = bb + f@A1 ----
    float o[19];
#pragma unroll
    for (int j = 0; j < 19; ++j) o[j] = RLW(OFF_BB + j);
#pragma unroll
    for (int e = 0; e < 32; ++e) {
        float fe = f[e];
#pragma unroll
        for (int j = 0; j < 19; ++j) o[j] = fmaf(fe, RLW(OFF_A1 + e*19 + j), o[j]);
    }

    // ---- gated part: a2 = cv + Sw*(sf@MVB) + w@GVB ----
    float a2[19];
#pragma unroll
    for (int j = 0; j < 19; ++j) a2[j] = RLW(OFF_CV + j);
    float c0 = Sw * s0, c1 = Sw * s1, c2 = Sw * s2;
#pragma unroll
    for (int j = 0; j < 19; ++j) a2[j] = fmaf(c0, RLW(OFF_MVB + j), a2[j]);
#pragma unroll
    for (int j = 0; j < 19; ++j) a2[j] = fmaf(c1, RLW(OFF_MVB + 19 + j), a2[j]);
#pragma unroll
    for (int j = 0; j < 19; ++j) a2[j] = fmaf(c2, RLW(OFF_MVB + 38 + j), a2[j]);
#pragma unroll
    for (int k = 0; k < 19; ++k) {
        float lk = l[k];
#pragma unroll
        for (int j = 0; j < 19; ++j) a2[j] = fmaf(lk, RLW(OFF_GVB + k*19 + j), a2[j]);
    }

    float vg = valid ? 1.f : 0.f;
    // ---- store 19 f32 ----
    float* op = out + (long)n * 19;
#pragma unroll
    for (int j = 0; j < 19; ++j) op[j] = fmaf(vg, a2[j], o[j]);
}

// =====================================================================
extern "C" void kernel_launch(void* const* d_in, const int* in_sizes, int n_in,
                              void* d_out, int out_size, void* d_ws, size_t ws_size,
                              hipStream_t stream) {
    const float* feat  = (const float*)d_in[0];
    const float* sflow = (const float*)d_in[1];
    const float* cpred = (const float*)d_in[2];
    const float* z     = (const float*)d_in[3];
    const float* sw1   = (const float*)d_in[4];
    const float* bn_g  = (const float*)d_in[5];
    const float* bn_b  = (const float*)d_in[6];
    const float* bn_m  = (const float*)d_in[7];
    const float* bn_v  = (const float*)d_in[8];
    const float* sw2   = (const float*)d_in[9];
    const float* sb2   = (const float*)d_in[10];
    const float* wq    = (const float*)d_in[11];
    const float* bq    = (const float*)d_in[12];
    const float* wk    = (const float*)d_in[13];
    const float* bk    = (const float*)d_in[14];
    const float* wv    = (const float*)d_in[15];
    const float* bv    = (const float*)d_in[16];
    const float* wo    = (const float*)d_in[17];
    const float* bo    = (const float*)d_in[18];
    const float* wt    = (const float*)d_in[19];
    const float* bt    = (const float*)d_in[20];
    const float* wout  = (const float*)d_in[21];
    const float* bout  = (const float*)d_in[22];
    const float* wgen  = (const float*)d_in[23];
    const float* bgen  = (const float*)d_in[24];

    float* W = (float*)d_ws;

    hipLaunchKernelGGL(pre_a, dim3(10), dim3(256), 0, stream,
                       z, sw1, bn_g, bn_b, bn_m, bn_v, sw2, sb2,
                       wq, bq, wk, bk, wv, wt, bt, wout, bout, wgen, bgen, W);
    hipLaunchKernelGGL(pre_b, dim3(6), dim3(256), 0, stream,
                       wq, bq, wk, wv, wo, W);
    hipLaunchKernelGGL(pre_c, dim3(5), dim3(256), 0, stream,
                       wq, bq, bv, bo, W);

    hipLaunchKernelGGL(main_k, dim3(NPTS / 256), dim3(256), 0, stream,
                       feat, sflow, cpred, W, (float*)d_out);
}

// Round 7
// 161.548 us; speedup vs baseline: 1.0289x; 1.0289x over previous
//
#include <hip/hip_runtime.h>

#define NPTS 131072

// ---------- d_ws layout (f32 dword indices) ----------
// gate region (exact f32, const-AS s_load path):
constexpr int OFF_SW1 = 0;        // 1024  select_w1 TRANSPOSED [c*32+e]
constexpr int OFF_BNS = 1024;     // 32
constexpr int OFF_BNH = 1056;     // 32
constexpr int OFF_SW2 = 1088;     // 32
constexpr int OFF_B2  = 1120;     // 1
// packed bf16-pair region (lane-distributed VGPR table, readlane path):
constexpr int PKB     = 1152;     // 923 dwords used (15 regs x 64 lanes = 960 cap)
//   pair indices within PKB:
//   [0..607]    (QG[e][k], A1[e][k])        p = e*19+k        x f[e]
//   [608..797]  (GVB[k][2h], GVB[k][2h+1])  p = 608+k*10+h    x l[k]
//   [798..827]  (MVB[m][2h], MVB[m][2h+1])  p = 798+m*10+h    x cm
//   [828..891]  e even: (QM[e][0],QM[e][1]); odd: (QM[e][2],QBV[e])  p=828+2e{,+1}
//   [892..910]  (QGB[k], BB[k])             p = 892+k         init qg/o
//   [911..920]  (CV[2h], CV[2h+1])          p = 911+h         init a2
//   [921]       (QMB0, QMB1)   [922] (QMB2, QBB)
// ---- intermediates ----
constexpr int XG   = 3072;  // 608  G[k*32+e]
constexpr int XA2  = 3680;  // 608  A2[d*19+j]
constexpr int XMK  = 4288;  // 96   Mk[m*32+c]
constexpr int XMV  = 4384;  // 96   Mv[m*32+c]
constexpr int XGK  = 4480;  // 608  Gk[k*32+c]
constexpr int XGV  = 5088;  // 608  Gv[k*32+c]
constexpr int XB   = 5696;  // 608  B[c*19+j]
constexpr int XA1  = 6304;  // 608  A1[e*19+j]
constexpr int XBB  = 6912;  // 19
constexpr int XQBV = 6931;  // 32
constexpr int XQBB = 6963;  // 1
constexpr int XQM  = 6964;  // 96
constexpr int XQMB = 7060;  // 3

#define CONST_AS __attribute__((address_space(4)))
__device__ __forceinline__ const CONST_AS float* to_const(const float* p) {
    return (const CONST_AS float*)p;
}

// bf16 round-to-nearest-even + pack2 (a -> low16, b -> high16)
__device__ __forceinline__ unsigned b16r(float x) {
    unsigned u = __float_as_uint(x);
    return (u + 0x7fffu + ((u >> 16) & 1u)) >> 16;
}
__device__ __forceinline__ float pk2(float a, float b) {
    return __uint_as_float(b16r(a) | (b16r(b) << 16));
}
// unpack (SALU on uniform input)
__device__ __forceinline__ float plo(unsigned d) { return __uint_as_float(d << 16); }
__device__ __forceinline__ float phi(unsigned d) { return __uint_as_float(d & 0xffff0000u); }

// =====================================================================
// Precompute stage A
// =====================================================================
__global__ __launch_bounds__(256) void pre_a(
    const float* __restrict__ z,
    const float* __restrict__ sw1,
    const float* __restrict__ bn_gamma, const float* __restrict__ bn_beta,
    const float* __restrict__ bn_mean,  const float* __restrict__ bn_var,
    const float* __restrict__ sw2,      const float* __restrict__ sb2,
    const float* __restrict__ wq, const float* __restrict__ bq,
    const float* __restrict__ wk, const float* __restrict__ bk,
    const float* __restrict__ wv,
    const float* __restrict__ wt, const float* __restrict__ bt,
    const float* __restrict__ wout, const float* __restrict__ bout,
    const float* __restrict__ wgen, const float* __restrict__ bgen,
    float* __restrict__ W)
{
    int i = blockIdx.x * 256 + threadIdx.x;
    if (i < 1024) {                       // SW1T[c*32+e] = sw1[e*32+c]
        W[OFF_SW1 + i] = sw1[(i & 31) * 32 + (i >> 5)];
    } else if (i < 1632) {                // A1, A2 -> intermediates
        int t = i - 1024, e = t / 19, j = t % 19;
        float a1 = 0.f, a2 = 0.f;
        for (int d = 0; d < 32; ++d) {
            float w_ = wout[d*19 + j];
            a1 += wt[e*32 + d] * w_;
            a2 += wt[(32 + e)*32 + d] * w_;
        }
        W[XA1 + t] = a1; W[XA2 + t] = a2;
    } else if (i < 2240) {                // G[k*32+e]
        int t = i - 1632, k = t >> 5, e = t & 31;
        float g = bgen[e];
        for (int d = 0; d < 16; ++d) g += z[d] * wgen[d*32 + e];
        W[XG + t] = g + wgen[(16 + k)*32 + e];
    } else if (i < 2336) {                // Mk, Mv
        int t = i - 2240, m = t >> 5, c = t & 31;
        float a = 0.f, b = 0.f;
        for (int e = 0; e < 32; ++e) {
            float wsr = wgen[(35 + m)*32 + e];
            a += wsr * wk[e*32 + c];
            b += wsr * wv[e*32 + c];
        }
        W[XMK + t] = a; W[XMV + t] = b;
    } else if (i < 2368) {                // BN fold + SW2 (gate, f32)
        int t = i - 2336;
        float scale = bn_gamma[t] / sqrtf(bn_var[t] + 1e-4f);
        W[OFF_BNS + t] = scale;
        W[OFF_BNH + t] = bn_beta[t] - bn_mean[t] * scale;
        W[OFF_SW2 + t] = sw2[t];
    } else if (i < 2387) {                // BB -> intermediate
        int t = i - 2368;
        float a = bout[t];
        for (int d = 0; d < 32; ++d) a += bt[d] * wout[d*19 + t];
        W[XBB + t] = a;
    } else if (i < 2419) {                // QBV -> intermediate
        int t = i - 2387;
        float a = 0.f;
        for (int c = 0; c < 32; ++c) a += wq[t*32 + c] * bk[c];
        W[XQBV + t] = a;
    } else if (i == 2419) {
        W[OFF_B2] = sb2[0];
    } else if (i == 2420) {               // QBB
        float a = 0.f;
        for (int c = 0; c < 32; ++c) a += bq[c] * bk[c];
        W[XQBB] = a;
    }
}

// =====================================================================
// Precompute stage B
// =====================================================================
__global__ __launch_bounds__(256) void pre_b(
    const float* __restrict__ wq, const float* __restrict__ bq,
    const float* __restrict__ wk, const float* __restrict__ wv,
    const float* __restrict__ wo,
    float* __restrict__ W)
{
    int i = blockIdx.x * 256 + threadIdx.x;
    if (i < 608) {                        // Gk, Gv  [k*32+c]
        int k = i >> 5, c = i & 31;
        float a = 0.f, b = 0.f;
        for (int e = 0; e < 32; ++e) {
            float g = W[XG + k*32 + e];
            a += g * wk[e*32 + c];
            b += g * wv[e*32 + c];
        }
        W[XGK + i] = a; W[XGV + i] = b;
    } else if (i < 1216) {                // B[c*19+j] = wo @ A2
        int t = i - 608, c = t / 19, j = t % 19;
        float a = 0.f;
        for (int d = 0; d < 32; ++d) a += wo[c*32 + d] * W[XA2 + d*19 + j];
        W[XB + t] = a;
    } else if (i < 1312) {                // QM[e*3+m]
        int t = i - 1216, e = t / 3, m = t % 3;
        float a = 0.f;
        for (int c = 0; c < 32; ++c) a += wq[e*32 + c] * W[XMK + m*32 + c];
        W[XQM + t] = a;
    } else if (i < 1315) {                // QMB[m]
        int m = i - 1312;
        float a = 0.f;
        for (int c = 0; c < 32; ++c) a += bq[c] * W[XMK + m*32 + c];
        W[XQMB + m] = a;
    }
}

// =====================================================================
// Precompute stage C: compute QG/QGB/GVB/MVB/CV and emit the PACKED table
// =====================================================================
__global__ __launch_bounds__(256) void pre_c(
    const float* __restrict__ wq, const float* __restrict__ bq,
    const float* __restrict__ bv, const float* __restrict__ bo,
    float* __restrict__ W)
{
    int p = blockIdx.x * 256 + threadIdx.x;
    if (p < 608) {                        // (QG[e][k], A1[e][k])
        int e = p / 19, k = p % 19;
        float qg = 0.f;
        for (int c = 0; c < 32; ++c) qg += wq[e*32 + c] * W[XGK + k*32 + c];
        W[PKB + p] = pk2(qg, W[XA1 + p]);
    } else if (p < 798) {                 // (GVB[k][2h], GVB[k][2h+1])
        int t = p - 608, k = t / 10, h = t % 10, j0 = 2*h;
        float g0 = 0.f, g1 = 0.f;
        for (int c = 0; c < 32; ++c) g0 += W[XGV + k*32 + c] * W[XB + c*19 + j0];
        if (j0 + 1 < 19)
            for (int c = 0; c < 32; ++c) g1 += W[XGV + k*32 + c] * W[XB + c*19 + j0 + 1];
        W[PKB + p] = pk2(g0, g1);
    } else if (p < 828) {                 // (MVB[m][2h], MVB[m][2h+1])
        int t = p - 798, m = t / 10, h = t % 10, j0 = 2*h;
        float g0 = 0.f, g1 = 0.f;
        for (int c = 0; c < 32; ++c) g0 += W[XMV + m*32 + c] * W[XB + c*19 + j0];
        if (j0 + 1 < 19)
            for (int c = 0; c < 32; ++c) g1 += W[XMV + m*32 + c] * W[XB + c*19 + j0 + 1];
        W[PKB + p] = pk2(g0, g1);
    } else if (p < 892) {                 // QM / QBV pairs
        int t = p - 828, e = t >> 1;
        if ((t & 1) == 0) W[PKB + p] = pk2(W[XQM + e*3 + 0], W[XQM + e*3 + 1]);
        else              W[PKB + p] = pk2(W[XQM + e*3 + 2], W[XQBV + e]);
    } else if (p < 911) {                 // (QGB[k], BB[k])
        int k = p - 892;
        float qgb = 0.f;
        for (int c = 0; c < 32; ++c) qgb += bq[c] * W[XGK + k*32 + c];
        W[PKB + p] = pk2(qgb, W[XBB + k]);
    } else if (p < 921) {                 // (CV[2h], CV[2h+1])
        int h = p - 911, j0 = 2*h;
        float c0 = 0.f, c1 = 0.f;
        for (int c = 0; c < 32; ++c) c0 += bv[c] * W[XB + c*19 + j0];
        for (int d = 0; d < 32; ++d) c0 += bo[d] * W[XA2 + d*19 + j0];
        if (j0 + 1 < 19) {
            for (int c = 0; c < 32; ++c) c1 += bv[c] * W[XB + c*19 + j0 + 1];
            for (int d = 0; d < 32; ++d) c1 += bo[d] * W[XA2 + d*19 + j0 + 1];
        }
        W[PKB + p] = pk2(c0, c1);
    } else if (p == 921) {
        W[PKB + p] = pk2(W[XQMB + 0], W[XQMB + 1]);
    } else if (p == 922) {
        W[PKB + p] = pk2(W[XQMB + 2], W[XQBB]);
    }
}

// =====================================================================
// Main kernel: gate in exact f32 via const-AS s_load; attention/output
// weights as bf16 pairs in 15 lane-distributed VGPRs, one readlane per
// TWO weights, SALU unpack, v_fmac with SGPR operand.
// =====================================================================
typedef float vf16 __attribute__((ext_vector_type(16)));
#define RLP(p) ((unsigned)__builtin_amdgcn_readlane(__float_as_int(tp[(p) >> 6]), (p) & 63))

__global__ __launch_bounds__(256, 1) void main_k(
    const float* __restrict__ feat,
    const float* __restrict__ sflow,
    const float* __restrict__ cpred,
    const float* __restrict__ Wg,
    float* __restrict__ out)
{
    const CONST_AS float* W = to_const(Wg);
    const int n = blockIdx.x * 256 + threadIdx.x;
    const int lane = threadIdx.x & 63;

    // ---- packed table -> 15 lane-distributed VGPRs ----
    vf16 tp;
#pragma unroll
    for (int r = 0; r < 15; ++r) tp[r] = Wg[PKB + r * 64 + lane];
    tp[15] = 0.f;

    // ---- inputs ----
    float f[32];
    const float4* fp = (const float4*)(feat + (long)n * 32);
#pragma unroll
    for (int g = 0; g < 8; ++g) {
        float4 v = fp[g];
        f[g*4+0] = v.x; f[g*4+1] = v.y; f[g*4+2] = v.z; f[g*4+3] = v.w;
    }
    float s0 = sflow[(long)n*3 + 0];
    float s1 = sflow[(long)n*3 + 1];
    float s2 = sflow[(long)n*3 + 2];
    bool tmask = (s0 != 0.f) | (s1 != 0.f) | (s2 != 0.f);

    // ---- softmax(coarse_pred) (f32) ----
    float cp[19];
#pragma unroll
    for (int k = 0; k < 19; ++k) cp[k] = cpred[(long)n*19 + k];
    float m1 = cp[0];
#pragma unroll
    for (int k = 1; k < 19; ++k) m1 = fmaxf(m1, cp[k]);
    float sum1 = 0.f;
#pragma unroll
    for (int k = 0; k < 19; ++k) { cp[k] = __expf(cp[k] - m1); sum1 += cp[k]; }
    float r1 = 1.f / sum1;
#pragma unroll
    for (int k = 0; k < 19; ++k) cp[k] *= r1;

    // ---- gate: exact f32 (const-AS s_load weights) ----
    float sacc = W[OFF_B2];
#pragma unroll
    for (int c = 0; c < 32; ++c) {
        float a = 0.f;
#pragma unroll
        for (int e = 0; e < 32; ++e) a = fmaf(f[e], W[OFF_SW1 + c*32 + e], a);
        float h = fmaf(a, W[OFF_BNS + c], W[OFF_BNH + c]);
        h = fmaxf(h, 0.f);
        sacc = fmaf(h, W[OFF_SW2 + c], sacc);
    }
    bool valid = tmask && (sacc < 1.3862943611198906f);  // sigmoid<0.8

    // ---- attention logits (bf16 packed weights) ----
    float qg[19], o[19];
#pragma unroll
    for (int k = 0; k < 19; ++k) { unsigned d = RLP(892 + k); qg[k] = plo(d); o[k] = phi(d); }
    float qm0, qm1, qm2, qb;
    { unsigned d = RLP(921); qm0 = plo(d); qm1 = phi(d); }
    { unsigned d = RLP(922); qm2 = plo(d); qb  = phi(d); }
#pragma unroll
    for (int e = 0; e < 32; ++e) {
        float fe = f[e];
#pragma unroll
        for (int k = 0; k < 19; ++k) {
            unsigned d = RLP(e*19 + k);
            qg[k] = fmaf(fe, plo(d), qg[k]);   // QG
            o[k]  = fmaf(fe, phi(d), o[k]);    // A1
        }
        { unsigned d = RLP(828 + 2*e);     qm0 = fmaf(fe, plo(d), qm0); qm1 = fmaf(fe, phi(d), qm1); }
        { unsigned d = RLP(828 + 2*e + 1); qm2 = fmaf(fe, plo(d), qm2); qb  = fmaf(fe, phi(d), qb); }
    }
    float qs = s0*qm0 + s1*qm1 + s2*qm2;

    const float RS = 0.17677669529663687f;  // 1/sqrt(32)
    float l[19];
#pragma unroll
    for (int k = 0; k < 19; ++k) l[k] = fmaf(cp[k], qg[k] + qs, qb) * RS;

    // ---- softmax(l); w[k]=attn[k]*cp[k]; Sw ----
    float m2 = l[0];
#pragma unroll
    for (int k = 1; k < 19; ++k) m2 = fmaxf(m2, l[k]);
    float sum2 = 0.f;
#pragma unroll
    for (int k = 0; k < 19; ++k) { l[k] = __expf(l[k] - m2); sum2 += l[k]; }
    float r2 = 1.f / sum2;
    float Sw = 0.f;
#pragma unroll
    for (int k = 0; k < 19; ++k) { l[k] = l[k] * r2 * cp[k]; Sw += l[k]; }

    // ---- gated part: a2 = CV + Sw*(sf@MVB) + w@GVB (bf16 pairs) ----
    float a2[20];
#pragma unroll
    for (int h = 0; h < 10; ++h) { unsigned d = RLP(911 + h); a2[2*h] = plo(d); a2[2*h+1] = phi(d); }
    float cms[3] = { Sw * s0, Sw * s1, Sw * s2 };
#pragma unroll
    for (int m = 0; m < 3; ++m) {
        float cm = cms[m];
#pragma unroll
        for (int h = 0; h < 10; ++h) {
            unsigned d = RLP(798 + m*10 + h);
            a2[2*h]   = fmaf(cm, plo(d), a2[2*h]);
            a2[2*h+1] = fmaf(cm, phi(d), a2[2*h+1]);
        }
    }
#pragma unroll
    for (int k = 0; k < 19; ++k) {
        float lk = l[k];
#pragma unroll
        for (int h = 0; h < 10; ++h) {
            unsigned d = RLP(608 + k*10 + h);
            a2[2*h]   = fmaf(lk, plo(d), a2[2*h]);
            a2[2*h+1] = fmaf(lk, phi(d), a2[2*h+1]);
        }
    }

    float vg = valid ? 1.f : 0.f;
    float* op = out + (long)n * 19;
#pragma unroll
    for (int j = 0; j < 19; ++j) op[j] = fmaf(vg, a2[j], o[j]);
}

// =====================================================================
extern "C" void kernel_launch(void* const* d_in, const int* in_sizes, int n_in,
                              void* d_out, int out_size, void* d_ws, size_t ws_size,
                              hipStream_t stream) {
    const float* feat  = (const float*)d_in[0];
    const float* sflow = (const float*)d_in[1];
    const float* cpred = (const float*)d_in[2];
    const float* z     = (const float*)d_in[3];
    const float* sw1   = (const float*)d_in[4];
    const float* bn_g  = (const float*)d_in[5];
    const float* bn_b  = (const float*)d_in[6];
    const float* bn_m  = (const float*)d_in[7];
    const float* bn_v  = (const float*)d_in[8];
    const float* sw2   = (const float*)d_in[9];
    const float* sb2   = (const float*)d_in[10];
    const float* wq    = (const float*)d_in[11];
    const float* bq    = (const float*)d_in[12];
    const float* wk    = (const float*)d_in[13];
    const float* bk    = (const float*)d_in[14];
    const float* wv    = (const float*)d_in[15];
    const float* bv    = (const float*)d_in[16];
    const float* wo    = (const float*)d_in[17];
    const float* bo    = (const float*)d_in[18];
    const float* wt    = (const float*)d_in[19];
    const float* bt    = (const float*)d_in[20];
    const float* wout  = (const float*)d_in[21];
    const float* bout  = (const float*)d_in[22];
    const float* wgen  = (const float*)d_in[23];
    const float* bgen  = (const float*)d_in[24];

    float* W = (float*)d_ws;

    hipLaunchKernelGGL(pre_a, dim3(10), dim3(256), 0, stream,
                       z, sw1, bn_g, bn_b, bn_m, bn_v, sw2, sb2,
                       wq, bq, wk, bk, wv, wt, bt, wout, bout, wgen, bgen, W);
    hipLaunchKernelGGL(pre_b, dim3(6), dim3(256), 0, stream,
                       wq, bq, wk, wv, wo, W);
    hipLaunchKernelGGL(pre_c, dim3(4), dim3(256), 0, stream,
                       wq, bq, bv, bo, W);

    hipLaunchKernelGGL(main_k, dim3(NPTS / 256), dim3(256), 0, stream,
                       feat, sflow, cpred, W, (float*)d_out);
}